// Round 3
// baseline (129.830 us; speedup 1.0000x reference)
//
#include <hip/hip_runtime.h>

#define NB 8
#define C_IN 64
#define HW 65536      // 256*256
#define CF 256
#define FHW 4096      // 64*64
#define NSEG 256
#define NGRP 8        // channel groups (32 ch each)
#define MBLK 64       // input blocks per batch
#define MAGIC 0x13579BDFu

// ws layout (floats):
// [0, 262144)            partial[NB][NGRP][FHW]      (1 MiB)
// [262144, 524288)       seg_part[NB][MBLK][2][NSEG] (1 MiB)  0=xs,1=cnt
// then: ppbits[NB] (u32), flags[NB] (u32)

__global__ __launch_bounds__(256) void k1(
    const float* __restrict__ input, const int* __restrict__ sp,
    const float* __restrict__ feat,
    float* __restrict__ partial, float* __restrict__ seg_part) {
  int b = blockIdx.y, t = threadIdx.x;
  if (blockIdx.x >= MBLK) {
    // featsum path: 16 blocks/batch, each 32 channels x 2048 px
    int e = blockIdx.x - MBLK;          // 0..15
    int g = e >> 1, half = e & 1;
    const float4* f4 = (const float4*)(feat + ((size_t)(b * CF + g * 32)) * FHW);
    float4* o4 = (float4*)partial + (size_t)(b * NGRP + g) * (FHW / 4);
#pragma unroll
    for (int j = 0; j < 2; ++j) {
      int q = half * 512 + j * 256 + t;
      float4 s = make_float4(0.f, 0.f, 0.f, 0.f);
#pragma unroll
      for (int c = 0; c < 32; ++c) {
        float4 v = f4[(size_t)c * (FHW / 4) + q];
        s.x += v.x; s.y += v.y; s.z += v.z; s.w += v.w;
      }
      o4[q] = s;
    }
    return;
  }
  // input path: histogram channel-sum and count per segment
  __shared__ float bin_x[NSEG], bin_c[NSEG];
  bin_x[t] = 0.f; bin_c[t] = 0.f;
  __syncthreads();
  int v0 = blockIdx.x * 256 + t;
  const float4* in4 = (const float4*)(input + (size_t)b * C_IN * HW);
  float4 xs = make_float4(0.f, 0.f, 0.f, 0.f);
#pragma unroll
  for (int c = 0; c < C_IN; ++c) {
    float4 v = in4[(size_t)c * (HW / 4) + v0];
    xs.x += v.x; xs.y += v.y; xs.z += v.z; xs.w += v.w;
  }
  int4 sv = ((const int4*)(sp + (size_t)b * HW))[v0];
  atomicAdd(&bin_x[sv.x], xs.x); atomicAdd(&bin_c[sv.x], 1.f);
  atomicAdd(&bin_x[sv.y], xs.y); atomicAdd(&bin_c[sv.y], 1.f);
  atomicAdd(&bin_x[sv.z], xs.z); atomicAdd(&bin_c[sv.z], 1.f);
  atomicAdd(&bin_x[sv.w], xs.w); atomicAdd(&bin_c[sv.w], 1.f);
  __syncthreads();
  float* sb = seg_part + (size_t)(b * MBLK + blockIdx.x) * 2 * NSEG;
  sb[t] = bin_x[t];
  sb[NSEG + t] = bin_c[t];
}

__global__ __launch_bounds__(1024) void k2(
    const int* __restrict__ sp, const float* __restrict__ partial,
    const float* __restrict__ seg_part,
    unsigned* __restrict__ ppbits, unsigned* __restrict__ flags,
    float* __restrict__ out) {
  __shared__ float fls[FHW];
  __shared__ float segs[2 * NSEG];     // xs-sum, cnt
  __shared__ float binf[NSEG];
  __shared__ float m1[NSEG], m2[NSEG];
  __shared__ float red[16];
  int b = blockIdx.x, t = threadIdx.x;

  {  // fls = sum of the 8 channel-group partials (1024 float4 = 4096 floats)
    const float4* p4 = (const float4*)(partial + (size_t)b * NGRP * FHW);
    float4 s = p4[t];
#pragma unroll
    for (int g = 1; g < NGRP; ++g) {
      float4 v = p4[g * (FHW / 4) + t];
      s.x += v.x; s.y += v.y; s.z += v.z; s.w += v.w;
    }
    ((float4*)fls)[t] = s;
  }
  if (t < 2 * NSEG) {
    const float* base = seg_part + (size_t)b * MBLK * 2 * NSEG + t;
    float s = 0.f;
#pragma unroll 8
    for (int k = 0; k < MBLK; ++k) s += base[(size_t)k * 2 * NSEG];
    segs[t] = s;
  }
  if (t < NSEG) binf[t] = 0.f;
  __syncthreads();

  // bilinear-sampled feature channel-sum, histogrammed by segment
  const int4* sp4 = (const int4*)(sp + (size_t)b * HW);
#pragma unroll 4
  for (int k = 0; k < 16; ++k) {
    int v4 = k * 1024 + t;
    int4 sv = sp4[v4];
    int p0 = v4 * 4;
    int y = p0 >> 8;
    float cy = (float)y * (63.0f / 255.0f);
    int iy = (int)cy; float ty = cy - (float)iy; int iy1 = min(iy + 1, 63);
    int svv[4] = {sv.x, sv.y, sv.z, sv.w};
#pragma unroll
    for (int kk = 0; kk < 4; ++kk) {
      int x = (p0 + kk) & 255;
      float cx = (float)x * (63.0f / 255.0f);
      int ix = (int)cx; float tx = cx - (float)ix; int ix1 = min(ix + 1, 63);
      float f00 = fls[iy * 64 + ix],  f10 = fls[iy1 * 64 + ix];
      float f01 = fls[iy * 64 + ix1], f11 = fls[iy1 * 64 + ix1];
      float a0 = f00 * (1.f - ty) + f10 * ty;
      float a1 = f01 * (1.f - ty) + f11 * ty;
      atomicAdd(&binf[svv[kk]], a0 * (1.f - tx) + a1 * tx);
    }
  }
  __syncthreads();
  if (t < NSEG) {
    float cnt = segs[NSEG + t];
    m1[t] = segs[t] / (cnt * 64.0f);
    m2[t] = binf[t] / (cnt * 256.0f);
  }
  __syncthreads();

  // pair sum over 256x256
  int i = t & 255, j0 = (t >> 8) * 64;
  float a1 = m1[i], a2 = m2[i], acc = 0.f;
#pragma unroll 8
  for (int jj = 0; jj < 64; ++jj) {
    int j = j0 + jj;
    acc += fabsf(fabsf(a1 - m1[j]) - fabsf(a2 - m2[j]));
  }
#pragma unroll
  for (int off = 32; off; off >>= 1) acc += __shfl_down(acc, off);
  if ((t & 63) == 0) red[t >> 6] = acc;
  __syncthreads();

  if (t == 0) {
    float s = 0.f;
#pragma unroll
    for (int w = 0; w < 16; ++w) s += red[w];
    __hip_atomic_store(&ppbits[b], __float_as_uint(s), __ATOMIC_RELAXED,
                       __HIP_MEMORY_SCOPE_AGENT);
    __hip_atomic_store(&flags[b], MAGIC, __ATOMIC_RELEASE,
                       __HIP_MEMORY_SCOPE_AGENT);
    if (b == 0) {
      float tot = s;
      for (int ob = 1; ob < NB; ++ob) {
        while (__hip_atomic_load(&flags[ob], __ATOMIC_ACQUIRE,
                                 __HIP_MEMORY_SCOPE_AGENT) != MAGIC) {}
        tot += __uint_as_float(__hip_atomic_load(
            &ppbits[ob], __ATOMIC_RELAXED, __HIP_MEMORY_SCOPE_AGENT));
      }
      out[0] = tot / 524288.0f;  // NB * NSEG * NSEG
      for (int ob = 0; ob < NB; ++ob)
        __hip_atomic_store(&flags[ob], 0u, __ATOMIC_RELAXED,
                           __HIP_MEMORY_SCOPE_AGENT);
    }
  }
}

extern "C" void kernel_launch(void* const* d_in, const int* in_sizes, int n_in,
                              void* d_out, int out_size, void* d_ws, size_t ws_size,
                              hipStream_t stream) {
  const float* input   = (const float*)d_in[0];
  const float* feature = (const float*)d_in[1];
  const int*   sp      = (const int*)d_in[2];
  float* ws = (float*)d_ws;
  float*    partial  = ws;
  float*    seg_part = ws + (size_t)NB * NGRP * FHW;
  unsigned* ppbits   = (unsigned*)(seg_part + (size_t)NB * MBLK * 2 * NSEG);
  unsigned* flags    = ppbits + NB;

  k1<<<dim3(MBLK + 16, NB), 256, 0, stream>>>(input, sp, feature, partial, seg_part);
  k2<<<dim3(NB), 1024, 0, stream>>>(sp, partial, seg_part, ppbits, flags,
                                    (float*)d_out);
}

// Round 5
// 53.363 us; speedup vs baseline: 2.4330x; 2.4330x over previous
//
#include <hip/hip_runtime.h>

#define NB 8
#define C_IN 64
#define HW 65536      // 256*256
#define CF 256
#define FHW 4096      // 64*64
#define NSEG 256
#define FBLK 16       // featsum blocks per batch
#define MBLK 64       // input blocks per batch
#define MAGIC 0x13579BDFu

// ws layout (floats):
// fsum     [NB][FHW]             @ 0        (32768)
// seg_part [NB][MBLK][2][NSEG]   @ 32768    (262144)   0=xsum,1=cnt
// binf_part[NB][8][NSEG]         @ 294912   (16384)
// u32: ppbits[NB], bflags[NB]    @ 311296

__global__ __launch_bounds__(256) void k1(
    const float* __restrict__ input, const int* __restrict__ sp,
    const float* __restrict__ feat,
    float* __restrict__ fsum, float* __restrict__ seg_part) {
  __shared__ float smem[1024];   // featsum: float4 lred[4][64] (4KB); input: 2*NSEG bins
  int b = blockIdx.y, t = threadIdx.x;

  if (blockIdx.x < FBLK) {
    // featsum: strip of 256 px (64 float4 cols), all 256 channels
    int e = blockIdx.x;
    int q = t & 63, cg = t >> 6;                  // 4 channel groups
    const float4* f4 = (const float4*)(feat + (size_t)b * CF * FHW);
    int col = e * 64 + q;
    float4 s = make_float4(0.f, 0.f, 0.f, 0.f);
#pragma unroll 8
    for (int c = cg; c < CF; c += 4) {
      float4 v = f4[(size_t)c * (FHW / 4) + col];
      s.x += v.x; s.y += v.y; s.z += v.z; s.w += v.w;
    }
    float4* lred = (float4*)smem;                  // [4][64] float4
    lred[cg * 64 + q] = s;
    __syncthreads();
    if (t < 64) {
      float4 a = lred[t], b1 = lred[64 + t], c1 = lred[128 + t], d = lred[192 + t];
      a.x += b1.x + c1.x + d.x; a.y += b1.y + c1.y + d.y;
      a.z += b1.z + c1.z + d.z; a.w += b1.w + c1.w + d.w;
      ((float4*)fsum)[(size_t)b * (FHW / 4) + e * 64 + t] = a;
    }
    return;
  }

  // input path: channel-sum + count histogram per segment
  int blk = blockIdx.x - FBLK;
  float* bin_x = smem;
  float* bin_c = smem + NSEG;
  bin_x[t] = 0.f; bin_c[t] = 0.f;
  __syncthreads();
  int v0 = blk * 256 + t;
  const float4* in4 = (const float4*)(input + (size_t)b * C_IN * HW);
  float4 xs = make_float4(0.f, 0.f, 0.f, 0.f);
#pragma unroll
  for (int c = 0; c < C_IN; ++c) {
    float4 v = in4[(size_t)c * (HW / 4) + v0];
    xs.x += v.x; xs.y += v.y; xs.z += v.z; xs.w += v.w;
  }
  int4 sv = ((const int4*)(sp + (size_t)b * HW))[v0];
  atomicAdd(&bin_x[sv.x], xs.x); atomicAdd(&bin_c[sv.x], 1.f);
  atomicAdd(&bin_x[sv.y], xs.y); atomicAdd(&bin_c[sv.y], 1.f);
  atomicAdd(&bin_x[sv.z], xs.z); atomicAdd(&bin_c[sv.z], 1.f);
  atomicAdd(&bin_x[sv.w], xs.w); atomicAdd(&bin_c[sv.w], 1.f);
  __syncthreads();
  float* sb = seg_part + (size_t)(b * MBLK + blk) * 2 * NSEG;
  sb[t] = bin_x[t];
  sb[NSEG + t] = bin_c[t];
}

__global__ __launch_bounds__(256) void k2(
    const int* __restrict__ sp, const float* __restrict__ fsum,
    float* __restrict__ binf_part) {
  __shared__ float fls[FHW];
  __shared__ float binf[NSEG];
  int e = blockIdx.x, b = blockIdx.y, t = threadIdx.x;
  {
    const float4* s4 = (const float4*)(fsum + (size_t)b * FHW);
    float4* d4 = (float4*)fls;
#pragma unroll
    for (int i = 0; i < 4; ++i) d4[i * 256 + t] = s4[i * 256 + t];
  }
  binf[t] = 0.f;
  __syncthreads();
  const int4* sp4 = (const int4*)(sp + (size_t)b * HW);
#pragma unroll
  for (int k = 0; k < 8; ++k) {
    int v4 = e * 2048 + k * 256 + t;
    int4 sv = sp4[v4];
    int p0 = v4 * 4;
    int y = p0 >> 8;
    float cy = (float)y * (63.0f / 255.0f);
    int iy = (int)cy; float ty = cy - (float)iy; int iy1 = min(iy + 1, 63);
    int svv[4] = {sv.x, sv.y, sv.z, sv.w};
#pragma unroll
    for (int kk = 0; kk < 4; ++kk) {
      int x = (p0 + kk) & 255;
      float cx = (float)x * (63.0f / 255.0f);
      int ix = (int)cx; float tx = cx - (float)ix; int ix1 = min(ix + 1, 63);
      float f00 = fls[iy * 64 + ix],  f10 = fls[iy1 * 64 + ix];
      float f01 = fls[iy * 64 + ix1], f11 = fls[iy1 * 64 + ix1];
      float a0 = f00 * (1.f - ty) + f10 * ty;
      float a1 = f01 * (1.f - ty) + f11 * ty;
      atomicAdd(&binf[svv[kk]], a0 * (1.f - tx) + a1 * tx);
    }
  }
  __syncthreads();
  binf_part[(size_t)(b * 8 + e) * NSEG + t] = binf[t];
}

__global__ __launch_bounds__(1024) void k3(
    const float* __restrict__ seg_part, const float* __restrict__ binf_part,
    unsigned* __restrict__ ppbits, unsigned* __restrict__ bflags,
    float* __restrict__ out) {
  __shared__ float s2[2 * NSEG];
  __shared__ float sf[NSEG];
  __shared__ float m1[NSEG], m2[NSEG];
  __shared__ float red[16];
  int b = blockIdx.x, t = threadIdx.x;
  if (t < 2 * NSEG) {
    const float* base = seg_part + (size_t)b * MBLK * 2 * NSEG + t;
    float s = 0.f;
#pragma unroll
    for (int k = 0; k < MBLK; ++k) s += base[k * 2 * NSEG];
    s2[t] = s;
  } else if (t < 2 * NSEG + NSEG) {
    int u = t - 2 * NSEG;
    const float* base = binf_part + (size_t)b * 8 * NSEG + u;
    float s = 0.f;
#pragma unroll
    for (int k = 0; k < 8; ++k) s += base[k * NSEG];
    sf[u] = s;
  }
  __syncthreads();
  if (t < NSEG) {
    float cnt = s2[NSEG + t];
    m1[t] = s2[t] / (cnt * 64.0f);
    m2[t] = sf[t] / (cnt * 256.0f);
  }
  __syncthreads();
  int i = t & 255, j0 = (t >> 8) * 64;
  float a1 = m1[i], a2 = m2[i], acc = 0.f;
#pragma unroll
  for (int jj = 0; jj < 64; ++jj) {
    int j = j0 + jj;
    acc += fabsf(fabsf(a1 - m1[j]) - fabsf(a2 - m2[j]));
  }
#pragma unroll
  for (int off = 32; off; off >>= 1) acc += __shfl_down(acc, off);
  if ((t & 63) == 0) red[t >> 6] = acc;
  __syncthreads();
  if (t == 0) {
    float s = 0.f;
#pragma unroll
    for (int w = 0; w < 16; ++w) s += red[w];
    __hip_atomic_store(&ppbits[b], __float_as_uint(s), __ATOMIC_RELAXED,
                       __HIP_MEMORY_SCOPE_AGENT);
    __hip_atomic_store(&bflags[b], MAGIC, __ATOMIC_RELEASE,
                       __HIP_MEMORY_SCOPE_AGENT);
    if (b == 0) {
      float tot = s;
      for (int ob = 1; ob < NB; ++ob) {
        while (__hip_atomic_load(&bflags[ob], __ATOMIC_ACQUIRE,
                                 __HIP_MEMORY_SCOPE_AGENT) != MAGIC) {}
        tot += __uint_as_float(__hip_atomic_load(
            &ppbits[ob], __ATOMIC_RELAXED, __HIP_MEMORY_SCOPE_AGENT));
      }
      out[0] = tot / 524288.0f;  // NB * NSEG * NSEG
      for (int ob = 0; ob < NB; ++ob)
        __hip_atomic_store(&bflags[ob], 0u, __ATOMIC_RELAXED,
                           __HIP_MEMORY_SCOPE_AGENT);
    }
  }
}

extern "C" void kernel_launch(void* const* d_in, const int* in_sizes, int n_in,
                              void* d_out, int out_size, void* d_ws, size_t ws_size,
                              hipStream_t stream) {
  const float* input   = (const float*)d_in[0];
  const float* feature = (const float*)d_in[1];
  const int*   sp      = (const int*)d_in[2];
  float* ws = (float*)d_ws;
  float*    fsum      = ws;
  float*    seg_part  = ws + (size_t)NB * FHW;
  float*    binf_part = seg_part + (size_t)NB * MBLK * 2 * NSEG;
  unsigned* ppbits    = (unsigned*)(binf_part + (size_t)NB * 8 * NSEG);
  unsigned* bflags    = ppbits + NB;

  k1<<<dim3(FBLK + MBLK, NB), 256, 0, stream>>>(input, sp, feature, fsum, seg_part);
  k2<<<dim3(8, NB), 256, 0, stream>>>(sp, fsum, binf_part);
  k3<<<dim3(NB), 1024, 0, stream>>>(seg_part, binf_part, ppbits, bflags,
                                    (float*)d_out);
}